// Round 2
// baseline (619.290 us; speedup 1.0000x reference)
//
#include <hip/hip_runtime.h>
#include <cstdint>
#include <cstddef>

#define N_NODES_C 100000
#define N_EDGES_C 1600000
#define LN_EPS_C 1e-5f
#define CLAMP_C 1.8f

__device__ __forceinline__ float readlane_f(float v, int l) {
  return __uint_as_float(__builtin_amdgcn_readlane(__float_as_uint(v), l));
}

__device__ __forceinline__ float wave_sum(float v) {
#pragma unroll
  for (int off = 32; off > 0; off >>= 1) v += __shfl_xor(v, off, 64);
  return v;
}

// ---------------- CSR build ----------------
__global__ void hist_kernel(const int* __restrict__ row, int* __restrict__ counts) {
  int stride = gridDim.x * blockDim.x;
  for (int e = blockIdx.x * blockDim.x + threadIdx.x; e < N_EDGES_C; e += stride)
    atomicAdd(&counts[row[e]], 1);
}

__global__ void scan1_kernel(const int* __restrict__ counts, int* __restrict__ rowstart,
                             int* __restrict__ bsums) {
  __shared__ int lds[256];
  int t = threadIdx.x;
  int base = blockIdx.x * 1024 + t * 4;
  int c0 = (base + 0 < N_NODES_C) ? counts[base + 0] : 0;
  int c1 = (base + 1 < N_NODES_C) ? counts[base + 1] : 0;
  int c2 = (base + 2 < N_NODES_C) ? counts[base + 2] : 0;
  int c3 = (base + 3 < N_NODES_C) ? counts[base + 3] : 0;
  int s = c0 + c1 + c2 + c3;
  lds[t] = s;
  __syncthreads();
#pragma unroll
  for (int off = 1; off < 256; off <<= 1) {
    int v = (t >= off) ? lds[t - off] : 0;
    __syncthreads();
    lds[t] += v;
    __syncthreads();
  }
  int incl = lds[t];
  int excl = incl - s;
  if (t == 255) bsums[blockIdx.x] = incl;
  if (base + 0 < N_NODES_C) rowstart[base + 0] = excl;
  excl += c0;
  if (base + 1 < N_NODES_C) rowstart[base + 1] = excl;
  excl += c1;
  if (base + 2 < N_NODES_C) rowstart[base + 2] = excl;
  excl += c2;
  if (base + 3 < N_NODES_C) rowstart[base + 3] = excl;
}

__global__ void scan2_kernel(int* __restrict__ bsums, int nb) {
  __shared__ int lds[128];
  int t = threadIdx.x;
  int v = (t < nb) ? bsums[t] : 0;
  lds[t] = v;
  __syncthreads();
#pragma unroll
  for (int off = 1; off < 128; off <<= 1) {
    int u = (t >= off) ? lds[t - off] : 0;
    __syncthreads();
    lds[t] += u;
    __syncthreads();
  }
  if (t < nb) bsums[t] = lds[t] - v;
}

__global__ void scan3_kernel(int* __restrict__ rowstart, const int* __restrict__ bsums) {
  int add = bsums[blockIdx.x];
  int base = blockIdx.x * 1024 + threadIdx.x * 4;
#pragma unroll
  for (int i = 0; i < 4; ++i)
    if (base + i < N_NODES_C) rowstart[base + i] += add;
}

__global__ void scatter_kernel(const int* __restrict__ row, const int* __restrict__ col,
                               const float* __restrict__ vals, const int* __restrict__ rowstart,
                               int* __restrict__ cursor, int* __restrict__ col_s,
                               float* __restrict__ val_s) {
  int stride = gridDim.x * blockDim.x;
  for (int e = blockIdx.x * blockDim.x + threadIdx.x; e < N_EDGES_C; e += stride) {
    int r = row[e];
    int p = rowstart[r] + atomicAdd(&cursor[r], 1);
    col_s[p] = col[e];
    val_s[p] = vals[e];
  }
}

// ---------------- clamp + LayerNorm + GEMM1 (100 -> 64) ----------------
// wave per node; W1 column for this lane's output feature held in 100 VGPRs.
__global__ __launch_bounds__(256) void ln_gemm1_kernel(
    const float* __restrict__ x, const float* __restrict__ gamma, const float* __restrict__ beta,
    const float* __restrict__ W1, const float* __restrict__ b1, float* __restrict__ y) {
  int lane = threadIdx.x & 63;
  int wid = blockIdx.x * (blockDim.x >> 6) + (threadIdx.x >> 6);
  int nw = gridDim.x * (blockDim.x >> 6);
  float w[100];
#pragma unroll
  for (int k = 0; k < 100; ++k) w[k] = W1[k * 64 + lane];
  float bias = b1[lane];
  float g0 = gamma[lane];
  float be0 = beta[lane];
  float g1 = (lane < 36) ? gamma[64 + lane] : 0.f;
  float be1 = (lane < 36) ? beta[64 + lane] : 0.f;
  for (int n = wid; n < N_NODES_C; n += nw) {
    const float* xr = x + (size_t)n * 100;
    float x0 = xr[lane];
    float x1 = (lane < 36) ? xr[64 + lane] : 0.f;
    x0 = fminf(fmaxf(x0, -CLAMP_C), CLAMP_C);
    x1 = fminf(fmaxf(x1, -CLAMP_C), CLAMP_C);
    float mu = wave_sum(x0 + x1) * 0.01f;  // x1 == 0 for lane >= 36
    float d0 = x0 - mu;
    float d1 = (lane < 36) ? (x1 - mu) : 0.f;
    float var = wave_sum(d0 * d0 + d1 * d1) * 0.01f;
    float inv = rsqrtf(var + LN_EPS_C);
    float xn0 = d0 * inv * g0 + be0;
    float xn1 = d1 * inv * g1 + be1;
    float acc = bias;
#pragma unroll
    for (int k = 0; k < 64; ++k) acc = fmaf(readlane_f(xn0, k), w[k], acc);
#pragma unroll
    for (int k = 0; k < 36; ++k) acc = fmaf(readlane_f(xn1, k), w[64 + k], acc);
    y[(size_t)n * 64 + lane] = acc;
  }
}

// ---------------- dense GEMM (64 -> DOUT), bias added ----------------
template <int DOUT>
__global__ __launch_bounds__(256) void gemm64_kernel(const float* __restrict__ a,
                                                     const float* __restrict__ W,
                                                     const float* __restrict__ b,
                                                     float* __restrict__ y) {
  int lane = threadIdx.x & 63;
  int wid = blockIdx.x * (blockDim.x >> 6) + (threadIdx.x >> 6);
  int nw = gridDim.x * (blockDim.x >> 6);
  float w[64];
#pragma unroll
  for (int k = 0; k < 64; ++k) w[k] = (lane < DOUT) ? W[k * DOUT + lane] : 0.f;
  float bias = (lane < DOUT) ? b[lane] : 0.f;
  for (int n = wid; n < N_NODES_C; n += nw) {
    float av = a[(size_t)n * 64 + lane];
    float acc = bias;
#pragma unroll
    for (int k = 0; k < 64; ++k) acc = fmaf(readlane_f(av, k), w[k], acc);
    if (lane < DOUT) y[(size_t)n * DOUT + lane] = acc;
  }
}

// ---------------- SpMM: out[n] = sum_e val_e * y[col_e], optional ELU ----------------
template <int D, bool ELU>
__global__ __launch_bounds__(256) void spmm_kernel(const int* __restrict__ rowstart,
                                                   const int* __restrict__ counts,
                                                   const int* __restrict__ col_s,
                                                   const float* __restrict__ val_s,
                                                   const float* __restrict__ y,
                                                   float* __restrict__ out) {
  int lane = threadIdx.x & 63;
  int wid = blockIdx.x * (blockDim.x >> 6) + (threadIdx.x >> 6);
  int nw = gridDim.x * (blockDim.x >> 6);
  for (int n = wid; n < N_NODES_C; n += nw) {
    int start = rowstart[n];
    int cnt = counts[n];
    float acc = 0.f;
    for (int base = 0; base < cnt; base += 64) {
      int m = cnt - base;
      if (m > 64) m = 64;
      int ce = 0;
      float ve = 0.f;
      if (lane < m) {
        ce = col_s[start + base + lane];
        ve = val_s[start + base + lane];
      }
      for (int j = 0; j < m; ++j) {
        int c = __builtin_amdgcn_readlane(ce, j);
        float v = readlane_f(ve, j);
        float yv = (D == 64 || lane < D) ? y[(size_t)c * D + lane] : 0.f;
        acc = fmaf(v, yv, acc);
      }
    }
    if (ELU) acc = (acc > 0.f) ? acc : expm1f(acc);
    if (D == 64 || lane < D) out[(size_t)n * D + lane] = acc;
  }
}

extern "C" void kernel_launch(void* const* d_in, const int* in_sizes, int n_in,
                              void* d_out, int out_size, void* d_ws, size_t ws_size,
                              hipStream_t stream) {
  const float* x = (const float*)d_in[0];
  const float* adj_vals = (const float*)d_in[1];
  const int* adj_row = (const int*)d_in[2];
  const int* adj_col = (const int*)d_in[3];
  const float* gamma = (const float*)d_in[4];
  const float* beta = (const float*)d_in[5];
  const float* W1 = (const float*)d_in[6];
  const float* b1 = (const float*)d_in[7];
  const float* W2 = (const float*)d_in[8];
  const float* b2 = (const float*)d_in[9];
  const float* W3 = (const float*)d_in[10];
  const float* b3 = (const float*)d_in[11];
  float* out = (float*)d_out;

  char* ws = (char*)d_ws;
  size_t off = 0;
  auto alloc = [&](size_t bytes) -> void* {
    void* p = ws + off;
    off += (bytes + 255) & ~(size_t)255;
    return p;
  };
  float* bufA = (float*)alloc(sizeof(float) * (size_t)N_NODES_C * 64);
  float* bufB = (float*)alloc(sizeof(float) * (size_t)N_NODES_C * 64);
  int* counts = (int*)alloc(sizeof(int) * N_NODES_C);
  int* cursor = (int*)alloc(sizeof(int) * N_NODES_C);
  int* rowstart = (int*)alloc(sizeof(int) * N_NODES_C);
  int* bsums = (int*)alloc(sizeof(int) * 256);
  int* col_s = (int*)alloc(sizeof(int) * N_EDGES_C);
  float* val_s = (float*)alloc(sizeof(float) * N_EDGES_C);

  hipMemsetAsync(counts, 0, sizeof(int) * N_NODES_C, stream);
  hipMemsetAsync(cursor, 0, sizeof(int) * N_NODES_C, stream);

  hist_kernel<<<2048, 256, 0, stream>>>(adj_row, counts);
  int nb = (N_NODES_C + 1023) / 1024;  // 98
  scan1_kernel<<<nb, 256, 0, stream>>>(counts, rowstart, bsums);
  scan2_kernel<<<1, 128, 0, stream>>>(bsums, nb);
  scan3_kernel<<<nb, 256, 0, stream>>>(rowstart, bsums);
  scatter_kernel<<<2048, 256, 0, stream>>>(adj_row, adj_col, adj_vals, rowstart, cursor,
                                           col_s, val_s);

  ln_gemm1_kernel<<<1024, 256, 0, stream>>>(x, gamma, beta, W1, b1, bufA);
  spmm_kernel<64, true><<<2048, 256, 0, stream>>>(rowstart, counts, col_s, val_s, bufA, bufB);
  gemm64_kernel<64><<<1024, 256, 0, stream>>>(bufB, W2, b2, bufA);
  spmm_kernel<64, true><<<2048, 256, 0, stream>>>(rowstart, counts, col_s, val_s, bufA, bufB);
  gemm64_kernel<47><<<1024, 256, 0, stream>>>(bufB, W3, b3, bufA);
  spmm_kernel<47, false><<<2048, 256, 0, stream>>>(rowstart, counts, col_s, val_s, bufA, out);
}